// Round 6
// baseline (114.591 us; speedup 1.0000x reference)
//
#include <hip/hip_runtime.h>
#include <float.h>
#include <math.h>

#define NSAMPLE 8192
#define KSEL 9          // K+1: keep 9 smallest incl. self
#define KNN 8
#define BLK 512
#define EPS_F 1e-12f

#define ROWS_PB 8                    // rows per block -> 1024 blocks
#define NBLOCKS (NSAMPLE / ROWS_PB)  // 1024
#define RPT 8                        // all 8 rows per thread (octant scan)
#define LANES 64
#define KQT 16                       // scan iters per wave (1024-cand octant / 64)
#define BNDI 4                       // bound iters per wave (256 of the octant)
#define WCAP 32                      // survivor cap per (wave,row) list
#define BP 129                       // bound minima stride (128 + 1 pad)
#define IDX_MASK 0x1FFFu             // low 13 bits = candidate index
#define VAL_MASK 0xFFFFE000u         // high 19 bits = d2 (sign+exp+10 mantissa)
#define PROW 73                      // merge-row stride (72 + 1 pad)
#define SROW 145                     // scratch stride (16*9 + 1)
#define SCALE (1.0f / (float)(NSAMPLE * KNN * 3))

__device__ __forceinline__ unsigned umn(unsigned a, unsigned b) { return a < b ? a : b; }
__device__ __forceinline__ unsigned umx(unsigned a, unsigned b) { return a > b ? a : b; }

// Branchless insert of x into descending-sorted s[0..8] (s[0]=worst, s[8]=best).
__device__ __forceinline__ void insert9(unsigned s[KSEL], unsigned x)
{
#pragma unroll
    for (int k = 0; k < KSEL - 1; ++k)
        s[k] = umx(s[k + 1], umn(x, s[k]));
    s[KSEL - 1] = umn(x, s[KSEL - 1]);
}

// Packed (d2 | idx). d2 clamped >= 0 so self packs minimal.
__device__ __forceinline__ unsigned pack_d2(float d2, int gidx)
{
    return (__float_as_uint(fmaxf(d2, 0.0f)) & VAL_MASK) | (unsigned)gidx;
}

// Force a wave-uniform float into an SGPR (frees per-lane VGPR copies).
__device__ __forceinline__ float sfl(float x)
{
    return __uint_as_float((unsigned)__builtin_amdgcn_readfirstlane(
        (int)__float_as_uint(x)));
}

// popcount(mask & lanes_below_me) in 2 VALU (v_mbcnt_lo/hi).
__device__ __forceinline__ unsigned mbcnt64(unsigned long long m)
{
    return __builtin_amdgcn_mbcnt_hi((unsigned)(m >> 32),
           __builtin_amdgcn_mbcnt_lo((unsigned)(m & 0xFFFFFFFFull), 0u));
}

// ---------------------------------------------------------------------------
// Kernel 1: one-time gather into compact L2-resident float4 arrays:
//   sm4 = (mean.xyz, |mean|^2), ss4 = (sh0.xyz, 0).
// ---------------------------------------------------------------------------
__global__ __launch_bounds__(256) void gather_k(
    const float* __restrict__ means, const float* __restrict__ sh0,
    const int* __restrict__ idx,
    float4* __restrict__ sm4, float4* __restrict__ ss4)
{
    int i = blockIdx.x * 256 + threadIdx.x;
    if (i >= NSAMPLE) return;
    int id = idx[i];
    const float* m = means + 3 * id;
    const float* s = sh0 + 3 * id;
    float mx = m[0], my = m[1], mz = m[2];
    sm4[i] = make_float4(mx, my, mz, fmaf(mx, mx, fmaf(my, my, mz * mz)));
    ss4[i] = make_float4(s[0], s[1], s[2], 0.0f);
}

// ---------------------------------------------------------------------------
// Kernel 2 (R22): R19 structure; scan = chunk-4 ping-pong with
// sched_barrier(0)-pinned clusters. History of the depth lever:
//   R19: compiler chose depth-2 -> VALUBusy 37%, 46.7us (latency-stalled).
//   R20: depth-16, all buffers live -> spill (FETCH 47MB), 80us.
//   R21: depth-6 "as written" + bounds(512,5): scheduler free to sink loads
//        (no fence binds them) and a ~100-VGPR budget -> mechanism likely
//        never executed; confounded regression.
// R22 makes depth STRUCTURAL:
//   - ping-pong chunks of 4 float4: {proc A | refill B} alternation; at each
//     proc-cluster the next chunk's loads have ~560cy of compute in flight
//     (>= 2x L2 latency). Peak buffer liveness 8 float4 = 32 VGPR.
//   - __builtin_amdgcn_sched_barrier(0) between every cluster: scheduler
//     cannot sink loads across (the documented pin for this).
//   - __launch_bounds__(512,8): 64-VGPR cap -> 4 blocks/CU, 8 waves/SIMD
//     (R19's verified occupancy). Est. alloc ~56 < 64.
// Tripwire: FETCH_SIZE must stay ~1.2MB, VGPR 52-64. Blowup => pivot to
// LDS-staged global_load_lds double-buffer next round.
// Screen/packing/dup semantics bit-inherited from R19 -> selection exact.
// ---------------------------------------------------------------------------
// Process rows R..R+3 (R = literal 0 or 4) of one candidate register Q.
#define QUAD(R, Q, CI)                                                        \
    {                                                                         \
        float v0 = fmaf(cX[(R) + 0], (Q).x, fmaf(cY[(R) + 0], (Q).y,          \
                   fmaf(cZ[(R) + 0], (Q).z, (Q).w)));                         \
        float v1 = fmaf(cX[(R) + 1], (Q).x, fmaf(cY[(R) + 1], (Q).y,          \
                   fmaf(cZ[(R) + 1], (Q).z, (Q).w)));                         \
        float v2 = fmaf(cX[(R) + 2], (Q).x, fmaf(cY[(R) + 2], (Q).y,          \
                   fmaf(cZ[(R) + 2], (Q).z, (Q).w)));                         \
        float v3 = fmaf(cX[(R) + 3], (Q).x, fmaf(cY[(R) + 3], (Q).y,          \
                   fmaf(cZ[(R) + 3], (Q).z, (Q).w)));                         \
        unsigned long long m0 = __ballot(v0 <= sb[(R) + 0]);                  \
        unsigned long long m1 = __ballot(v1 <= sb[(R) + 1]);                  \
        unsigned long long m2 = __ballot(v2 <= sb[(R) + 2]);                  \
        unsigned long long m3 = __ballot(v3 <= sb[(R) + 3]);                  \
        if (m0) {                                                             \
            unsigned pos = base[(R) + 0] + mbcnt64(m0);                       \
            if ((v0 <= sb[(R) + 0]) && pos < WCAP)                            \
                wl[(w * RPT + (R) + 0) * WCAP + pos] =                        \
                    pack_d2(v0 + cW[(R) + 0], (CI));                          \
            base[(R) + 0] += (unsigned)__popcll(m0);                          \
        }                                                                     \
        if (m1) {                                                             \
            unsigned pos = base[(R) + 1] + mbcnt64(m1);                       \
            if ((v1 <= sb[(R) + 1]) && pos < WCAP)                            \
                wl[(w * RPT + (R) + 1) * WCAP + pos] =                        \
                    pack_d2(v1 + cW[(R) + 1], (CI));                          \
            base[(R) + 1] += (unsigned)__popcll(m1);                          \
        }                                                                     \
        if (m2) {                                                             \
            unsigned pos = base[(R) + 2] + mbcnt64(m2);                       \
            if ((v2 <= sb[(R) + 2]) && pos < WCAP)                            \
                wl[(w * RPT + (R) + 2) * WCAP + pos] =                        \
                    pack_d2(v2 + cW[(R) + 2], (CI));                          \
            base[(R) + 2] += (unsigned)__popcll(m2);                          \
        }                                                                     \
        if (m3) {                                                             \
            unsigned pos = base[(R) + 3] + mbcnt64(m3);                       \
            if ((v3 <= sb[(R) + 3]) && pos < WCAP)                            \
                wl[(w * RPT + (R) + 3) * WCAP + pos] =                        \
                    pack_d2(v3 + cW[(R) + 3], (CI));                          \
            base[(R) + 3] += (unsigned)__popcll(m3);                          \
        }                                                                     \
    }

// One candidate register against all 8 rows.
#define CAND(Q, KI)                                                           \
    {                                                                         \
        const int ci = s0 + (KI) * LANES + lane;                              \
        QUAD(0, Q, ci)                                                        \
        QUAD(4, Q, ci)                                                        \
    }

#define SCHED_FENCE() __builtin_amdgcn_sched_barrier(0)

__global__ __launch_bounds__(BLK, 8) void main_k(
    const float4* __restrict__ sm4, const float4* __restrict__ ss4,
    float* __restrict__ partial)
{
    __shared__ unsigned wl[8 * RPT * WCAP];       // 8 KB private survivor lists
    __shared__ unsigned wcnt[8 * RPT];
    __shared__ unsigned bpart[ROWS_PB * BP];      // 4.1 KB bound minima (folded)
    __shared__ unsigned scratch[ROWS_PB * SROW];  // 4.6 KB bound-merge scratch
    __shared__ unsigned partS[ROWS_PB * PROW];    // 2.3 KB merge scratch 2
    __shared__ unsigned bnd[ROWS_PB];
    __shared__ float    red[ROWS_PB];

    const int t = threadIdx.x;
    const int lane = t & (LANES - 1);
    const int w = t >> 6;                       // 0..7 (wave id = octant)

    // Own-row coefficients -> SGPRs (wave-uniform; canonical d2 = s + cW
    // where s = fmaf(cX,qx, fmaf(cY,qy, fmaf(cZ,qz, qw)))).
    float cX[RPT], cY[RPT], cZ[RPT], cW[RPT];
#pragma unroll
    for (int i = 0; i < RPT; ++i) {
        float4 p = sm4[blockIdx.x * ROWS_PB + i];
        cX[i] = sfl(-2.0f * p.x);
        cY[i] = sfl(-2.0f * p.y);
        cZ[i] = sfl(-2.0f * p.z);
        cW[i] = sfl(p.w);
    }

    // ---- Bound: per-lane packed min over 4-cand slices of the octant's
    // first 256 cands (8 octants -> 2048-cand sample). Fold lanes ^32,^16
    // -> 128 minima/row (each the min of 16 distinct candidates).
    {
        unsigned pm[RPT];
#pragma unroll
        for (int i = 0; i < RPT; ++i) pm[i] = 0xFFFFFFFFu;
        const int b0 = w * (KQT * LANES);
        const float4* __restrict__ bp = sm4 + b0 + lane;
        float4 q0 = bp[0 * LANES];
        float4 q1 = bp[1 * LANES];
        float4 q2 = bp[2 * LANES];
        float4 q3 = bp[3 * LANES];
#pragma unroll
        for (int i = 0; i < RPT; ++i) {
            float s = fmaf(cX[i], q0.x,
                      fmaf(cY[i], q0.y, fmaf(cZ[i], q0.z, q0.w)));
            pm[i] = umn(pm[i], pack_d2(s + cW[i], b0 + 0 * LANES + lane));
        }
#pragma unroll
        for (int i = 0; i < RPT; ++i) {
            float s = fmaf(cX[i], q1.x,
                      fmaf(cY[i], q1.y, fmaf(cZ[i], q1.z, q1.w)));
            pm[i] = umn(pm[i], pack_d2(s + cW[i], b0 + 1 * LANES + lane));
        }
#pragma unroll
        for (int i = 0; i < RPT; ++i) {
            float s = fmaf(cX[i], q2.x,
                      fmaf(cY[i], q2.y, fmaf(cZ[i], q2.z, q2.w)));
            pm[i] = umn(pm[i], pack_d2(s + cW[i], b0 + 2 * LANES + lane));
        }
#pragma unroll
        for (int i = 0; i < RPT; ++i) {
            float s = fmaf(cX[i], q3.x,
                      fmaf(cY[i], q3.y, fmaf(cZ[i], q3.z, q3.w)));
            pm[i] = umn(pm[i], pack_d2(s + cW[i], b0 + 3 * LANES + lane));
        }
#pragma unroll
        for (int i = 0; i < RPT; ++i) {
            pm[i] = umn(pm[i], (unsigned)__shfl_xor((int)pm[i], 32, 64));
            pm[i] = umn(pm[i], (unsigned)__shfl_xor((int)pm[i], 16, 64));
        }
        if (lane < 16) {
#pragma unroll
            for (int i = 0; i < RPT; ++i)
                bpart[i * BP + w * 16 + lane] = pm[i];
        }
    }
    __syncthreads();

    // Merge 128 minima/row -> bnd = 9th smallest (valid upper bound on the
    // row's true 9th: the 9 minima below it are 9 distinct candidates).
    if (t < 128) {                              // stage 1: 8 rows x 16 groups
        const int r1 = t & (ROWS_PB - 1);
        const int g = t >> 3;                   // 0..15
        unsigned s[KSEL];
#pragma unroll
        for (int k = 0; k < KSEL; ++k) s[k] = 0xFFFFFFFFu;
#pragma unroll
        for (int e = 0; e < 8; ++e)
            insert9(s, bpart[r1 * BP + g * 8 + e]);
#pragma unroll
        for (int k = 0; k < KSEL; ++k)
            scratch[r1 * SROW + g * KSEL + k] = s[k];
    }
    __syncthreads();
    if (t < 64) {                               // stage 2: 8 rows x 8 groups
        const int r1 = t & (ROWS_PB - 1);
        const int mg = t >> 3;                  // 0..7
        unsigned m[KSEL];
#pragma unroll
        for (int k = 0; k < KSEL; ++k) m[k] = 0xFFFFFFFFu;
#pragma unroll
        for (int e = 0; e < 2 * KSEL; ++e)
            insert9(m, scratch[r1 * SROW + (2 * mg) * KSEL + e]);
#pragma unroll
        for (int k = 0; k < KSEL; ++k)
            partS[r1 * PROW + mg * KSEL + k] = m[k];
    }
    __syncthreads();
    if (t < ROWS_PB) {                          // stage 3: 72 -> 9th
        unsigned m[KSEL];
#pragma unroll
        for (int k = 0; k < KSEL; ++k) m[k] = 0xFFFFFFFFu;
#pragma unroll
        for (int e = 0; e < 8 * KSEL; ++e)
            insert9(m, partS[t * PROW + e]);
        bnd[t] = m[0];
    }
    __syncthreads();

    // s-space screen bound: pack(d2)|idx <= b requires d2 <= bf where
    // bf = uint_as_float(b | IDX_MASK) (positive floats: uint order == float
    // order). d2 = fl(s + cW) <= bf  ==>  s <= (bf - cW) + ~ulp slack; the
    // relative loosening (on bf AND the difference) keeps sb a superset
    // bound under all cancellation cases. Extras are harmless.
    float sb[RPT];
#pragma unroll
    for (int i = 0; i < RPT; ++i) {
        float bfv = __uint_as_float(bnd[i] | IDX_MASK);
        float D = bfv - cW[i];
        sb[i] = sfl(D + (bfv + fabsf(D)) * 6.0e-7f + 1e-33f);
    }

    // ---- Scan: chunk-4 ping-pong, sched_barrier-pinned clusters ----------
    // {A preloaded, B preloaded} -> proc A(k0..3) | refill A(k8..11) ->
    // proc B(k4..7) | refill B(k12..15) -> proc A -> proc B.
    // Every proc cluster runs with the next chunk's 4 loads in flight
    // (~560cy compute cover vs ~300cy L2 latency). Peak liveness 8 float4.
    unsigned base[RPT];
#pragma unroll
    for (int i = 0; i < RPT; ++i) base[i] = 0u;

    const int s0 = w * (KQT * LANES);
    const float4* __restrict__ qp = sm4 + s0 + lane;

    float4 A0 = qp[0 * LANES], A1 = qp[1 * LANES];
    float4 A2 = qp[2 * LANES], A3 = qp[3 * LANES];
    float4 B0 = qp[4 * LANES], B1 = qp[5 * LANES];
    float4 B2 = qp[6 * LANES], B3 = qp[7 * LANES];
    SCHED_FENCE();
    CAND(A0, 0)  CAND(A1, 1)  CAND(A2, 2)  CAND(A3, 3)
    SCHED_FENCE();
    A0 = qp[ 8 * LANES];  A1 = qp[ 9 * LANES];
    A2 = qp[10 * LANES];  A3 = qp[11 * LANES];
    SCHED_FENCE();
    CAND(B0, 4)  CAND(B1, 5)  CAND(B2, 6)  CAND(B3, 7)
    SCHED_FENCE();
    B0 = qp[12 * LANES];  B1 = qp[13 * LANES];
    B2 = qp[14 * LANES];  B3 = qp[15 * LANES];
    SCHED_FENCE();
    CAND(A0,  8)  CAND(A1,  9)  CAND(A2, 10)  CAND(A3, 11)
    SCHED_FENCE();
    CAND(B0, 12)  CAND(B1, 13)  CAND(B2, 14)  CAND(B3, 15)

    if (lane == 0) {
#pragma unroll
        for (int i = 0; i < RPT; ++i)
            wcnt[w * RPT + i] = umn(base[i], WCAP);
    }
    __syncthreads();                             // survivor lists complete

    // ---- Select: 64 tasks, each merges one (wave,row) list ---------------
    if (t < 64) {
        const int r1 = t & (ROWS_PB - 1);        // row
        const int wv = t >> 3;                   // 0..7 octant wave
        const int li = wv * RPT + r1;
        const unsigned n = wcnt[li];
        unsigned s[KSEL];
#pragma unroll
        for (int k = 0; k < KSEL; ++k) s[k] = 0xFFFFFFFFu;
        for (unsigned k = 0; k < n; ++k)
            insert9(s, wl[li * WCAP + k]);
#pragma unroll
        for (int k = 0; k < KSEL; ++k)
            partS[r1 * PROW + wv * KSEL + k] = s[k];
    }
    __syncthreads();

    if (t < ROWS_PB) {                          // final 72-merge + epilogue
        unsigned m[KSEL];
#pragma unroll
        for (int k = 0; k < KSEL; ++k) m[k] = 0xFFFFFFFFu;
#pragma unroll
        for (int e = 0; e < 8 * KSEL; ++e)
            insert9(m, partS[t * PROW + e]);

        // m[8] = global min (self, or identical-coordinate dup whose term is
        // 0 either way) -> dropped. m[0..7] = the 8 neighbors.
        const int gr = blockIdx.x * ROWS_PB + t;
        float4 pm4 = sm4[gr];
        float4 ps4 = ss4[gr];
        float acc = 0.0f;
#pragma unroll
        for (int k = 0; k < KNN; ++k) {
            int j = (int)(m[k] & IDX_MASK);
            float4 qm = sm4[j];
            float dx = pm4.x - qm.x, dy = pm4.y - qm.y, dz = pm4.z - qm.z;
            float d2 = fmaf(dx, dx, fmaf(dy, dy, dz * dz));
            float d = sqrtf(fmaxf(d2, EPS_F));
            float wgt = expf(-d);
            float4 qs = ss4[j];
            float ax = ps4.x - qs.x, ay = ps4.y - qs.y, az = ps4.z - qs.z;
            acc += wgt * (ax * ax + ay * ay + az * az);
        }
        red[t] = acc;
    }
    __syncthreads();
    if (t == 0) {
        float ssum = 0.0f;
#pragma unroll
        for (int i = 0; i < ROWS_PB; ++i) ssum += red[i];
        partial[blockIdx.x] = ssum;              // plain store
    }
}

// ---------------------------------------------------------------------------
// Kernel 3: reduce 1024 block partials -> scalar (cost ~0, proven R15;
// kept deterministic/order-identical so the output stays bit-exact).
// ---------------------------------------------------------------------------
__global__ __launch_bounds__(256) void reduce_k(
    const float* __restrict__ partial, float* __restrict__ out)
{
    __shared__ float sbuf[4];
    int t = threadIdx.x;
    float v = 0.0f;
    for (int i = t; i < NBLOCKS; i += 256) v += partial[i];
    for (int off = 32; off > 0; off >>= 1) v += __shfl_down(v, off);
    if ((t & 63) == 0) sbuf[t >> 6] = v;
    __syncthreads();
    if (t == 0) {
        float s = sbuf[0] + sbuf[1] + sbuf[2] + sbuf[3];
        out[0] = s * SCALE;
    }
}

// ---------------------------------------------------------------------------
extern "C" void kernel_launch(void* const* d_in, const int* in_sizes, int n_in,
                              void* d_out, int out_size, void* d_ws, size_t ws_size,
                              hipStream_t stream)
{
    const float* means = (const float*)d_in[0];
    const float* sh0   = (const float*)d_in[1];
    const int*   idxp  = (const int*)d_in[2];

    float4* sm4 = (float4*)d_ws;                 // 128 KB
    float4* ss4 = sm4 + NSAMPLE;                 // 128 KB
    float*  partial = (float*)(ss4 + NSAMPLE);   // 4 KB

    gather_k<<<NSAMPLE / 256, 256, 0, stream>>>(means, sh0, idxp, sm4, ss4);
    main_k<<<NBLOCKS, BLK, 0, stream>>>(sm4, ss4, partial);
    reduce_k<<<1, 256, 0, stream>>>(partial, (float*)d_out);
}

// Round 7
// 106.717 us; speedup vs baseline: 1.0738x; 1.0738x over previous
//
#include <hip/hip_runtime.h>
#include <float.h>
#include <math.h>

#define NSAMPLE 8192
#define KSEL 9          // K+1: keep 9 smallest incl. self
#define KNN 8
#define BLK 512
#define EPS_F 1e-12f

#define ROWS_PB 8                    // rows per block -> 1024 blocks
#define NBLOCKS (NSAMPLE / ROWS_PB)  // 1024
#define RPT 8                        // all 8 rows per thread (octant scan)
#define LANES 64
#define KQT 16                       // scan iters per wave (1024-cand octant / 64)
#define CHUNK 128                    // staged cands per chunk (2 per lane)
#define NCHUNK (1024 / CHUNK)        // 8
#define BNDI 4                       // bound iters per wave (256 of the octant)
#define WCAP 32                      // survivor cap per (wave,row) list
#define BP 129                       // bound minima stride (128 + 1 pad)
#define IDX_MASK 0x1FFFu             // low 13 bits = candidate index
#define VAL_MASK 0xFFFFE000u         // high 19 bits = d2 (sign+exp+10 mantissa)
#define PROW 73                      // merge-row stride (72 + 1 pad)
#define SROW 145                     // scratch stride (16*9 + 1)
#define SCALE (1.0f / (float)(NSAMPLE * KNN * 3))

__device__ __forceinline__ unsigned umn(unsigned a, unsigned b) { return a < b ? a : b; }
__device__ __forceinline__ unsigned umx(unsigned a, unsigned b) { return a > b ? a : b; }

// Branchless insert of x into descending-sorted s[0..8] (s[0]=worst, s[8]=best).
__device__ __forceinline__ void insert9(unsigned s[KSEL], unsigned x)
{
#pragma unroll
    for (int k = 0; k < KSEL - 1; ++k)
        s[k] = umx(s[k + 1], umn(x, s[k]));
    s[KSEL - 1] = umn(x, s[KSEL - 1]);
}

// Packed (d2 | idx). d2 clamped >= 0 so self packs minimal.
__device__ __forceinline__ unsigned pack_d2(float d2, int gidx)
{
    return (__float_as_uint(fmaxf(d2, 0.0f)) & VAL_MASK) | (unsigned)gidx;
}

// Force a wave-uniform float into an SGPR (frees per-lane VGPR copies).
__device__ __forceinline__ float sfl(float x)
{
    return __uint_as_float((unsigned)__builtin_amdgcn_readfirstlane(
        (int)__float_as_uint(x)));
}

// popcount(mask & lanes_below_me) in 2 VALU (v_mbcnt_lo/hi).
__device__ __forceinline__ unsigned mbcnt64(unsigned long long m)
{
    return __builtin_amdgcn_mbcnt_hi((unsigned)(m >> 32),
           __builtin_amdgcn_mbcnt_lo((unsigned)(m & 0xFFFFFFFFull), 0u));
}

// Direct global->LDS DMA (gfx950): per-lane global src, wave-uniform LDS
// base; HW writes lane i's 16B at base + i*16. No VGPR destination =>
// no register-allocator involvement (the R20/R22 spill failure mode is
// structurally impossible).
__device__ __forceinline__ void load_lds16(const float4* g, float4* l)
{
    __builtin_amdgcn_global_load_lds(
        (const __attribute__((address_space(1))) void*)g,
        (__attribute__((address_space(3))) void*)l, 16, 0, 0);
}

// ---------------------------------------------------------------------------
// Kernel 1: one-time gather into compact L2-resident float4 arrays:
//   sm4 = (mean.xyz, |mean|^2), ss4 = (sh0.xyz, 0).
// ---------------------------------------------------------------------------
__global__ __launch_bounds__(256) void gather_k(
    const float* __restrict__ means, const float* __restrict__ sh0,
    const int* __restrict__ idx,
    float4* __restrict__ sm4, float4* __restrict__ ss4)
{
    int i = blockIdx.x * 256 + threadIdx.x;
    if (i >= NSAMPLE) return;
    int id = idx[i];
    const float* m = means + 3 * id;
    const float* s = sh0 + 3 * id;
    float mx = m[0], my = m[1], mz = m[2];
    sm4[i] = make_float4(mx, my, mz, fmaf(mx, mx, fmaf(my, my, mz * mz)));
    ss4[i] = make_float4(s[0], s[1], s[2], 0.0f);
}

// ---------------------------------------------------------------------------
// Kernel 2 (R23): R19 compute structure; the scan's candidate stream now
// flows through LDS via global_load_lds + counted vmcnt (T3/T4 pattern).
// Why: R19-R22 proved the VGPR-held deep-prefetch mechanism cannot be
// expressed through hipcc's regalloc (R20/R22 spilled, R21 got sunk); the
// load-latency hypothesis itself was never executed. This design removes
// the register destination from the loads entirely:
//   - per wave: 2 x 2KB LDS buffers; chunk = 128 cands (2/lane).
//   - loop: issue chunk c+1 (2 x global_load_lds, fire-and-forget) ->
//     s_waitcnt vmcnt(2) (chunk c retired in-order; c+1's 2 loads stay in
//     flight ACROSS the body) -> ds_read_b128 x2 -> verified QUAD x4.
//     Issue->consume distance = one full chunk (~500cy) >= 2x L2 latency.
//   - last iter over-issues one chunk into the dead buffer (global reads
//     land in ss4 -- allocated, never consumed) to keep the body uniform.
//   - buffers wave-private: no barriers; no other VMEM ops in the loop, so
//     the vmcnt arithmetic is exact (loads retire in order, m135).
// LDS 52.4KB -> 3 blocks/CU (75% occ) -- acceptable: hiding is structural.
// Tripwire: FETCH ~1.2-1.5MB / WRITE ~32KB / VGPR ~40 (no spill).
// Screen/packing/dup semantics bit-inherited from R19 -> selection exact.
// ---------------------------------------------------------------------------
// Process rows R..R+3 (R = literal 0 or 4) of one candidate register Q.
#define QUAD(R, Q, CI)                                                        \
    {                                                                         \
        float v0 = fmaf(cX[(R) + 0], (Q).x, fmaf(cY[(R) + 0], (Q).y,          \
                   fmaf(cZ[(R) + 0], (Q).z, (Q).w)));                         \
        float v1 = fmaf(cX[(R) + 1], (Q).x, fmaf(cY[(R) + 1], (Q).y,          \
                   fmaf(cZ[(R) + 1], (Q).z, (Q).w)));                         \
        float v2 = fmaf(cX[(R) + 2], (Q).x, fmaf(cY[(R) + 2], (Q).y,          \
                   fmaf(cZ[(R) + 2], (Q).z, (Q).w)));                         \
        float v3 = fmaf(cX[(R) + 3], (Q).x, fmaf(cY[(R) + 3], (Q).y,          \
                   fmaf(cZ[(R) + 3], (Q).z, (Q).w)));                         \
        unsigned long long m0 = __ballot(v0 <= sb[(R) + 0]);                  \
        unsigned long long m1 = __ballot(v1 <= sb[(R) + 1]);                  \
        unsigned long long m2 = __ballot(v2 <= sb[(R) + 2]);                  \
        unsigned long long m3 = __ballot(v3 <= sb[(R) + 3]);                  \
        if (m0) {                                                             \
            unsigned pos = base[(R) + 0] + mbcnt64(m0);                       \
            if ((v0 <= sb[(R) + 0]) && pos < WCAP)                            \
                wl[(w * RPT + (R) + 0) * WCAP + pos] =                        \
                    pack_d2(v0 + cW[(R) + 0], (CI));                          \
            base[(R) + 0] += (unsigned)__popcll(m0);                          \
        }                                                                     \
        if (m1) {                                                             \
            unsigned pos = base[(R) + 1] + mbcnt64(m1);                       \
            if ((v1 <= sb[(R) + 1]) && pos < WCAP)                            \
                wl[(w * RPT + (R) + 1) * WCAP + pos] =                        \
                    pack_d2(v1 + cW[(R) + 1], (CI));                          \
            base[(R) + 1] += (unsigned)__popcll(m1);                          \
        }                                                                     \
        if (m2) {                                                             \
            unsigned pos = base[(R) + 2] + mbcnt64(m2);                       \
            if ((v2 <= sb[(R) + 2]) && pos < WCAP)                            \
                wl[(w * RPT + (R) + 2) * WCAP + pos] =                        \
                    pack_d2(v2 + cW[(R) + 2], (CI));                          \
            base[(R) + 2] += (unsigned)__popcll(m2);                          \
        }                                                                     \
        if (m3) {                                                             \
            unsigned pos = base[(R) + 3] + mbcnt64(m3);                       \
            if ((v3 <= sb[(R) + 3]) && pos < WCAP)                            \
                wl[(w * RPT + (R) + 3) * WCAP + pos] =                        \
                    pack_d2(v3 + cW[(R) + 3], (CI));                          \
            base[(R) + 3] += (unsigned)__popcll(m3);                          \
        }                                                                     \
    }

__global__ __launch_bounds__(BLK, 6) void main_k(
    const float4* __restrict__ sm4, const float4* __restrict__ ss4,
    float* __restrict__ partial)
{
    __shared__ float4   stg[8][2][CHUNK];         // 32 KB staging (per-wave dbuf)
    __shared__ unsigned wl[8 * RPT * WCAP];       // 8 KB private survivor lists
    __shared__ unsigned wcnt[8 * RPT];
    __shared__ unsigned bpart[ROWS_PB * BP];      // 4.1 KB bound minima (folded)
    __shared__ unsigned scratch[ROWS_PB * SROW];  // 4.6 KB bound-merge scratch
    __shared__ unsigned partS[ROWS_PB * PROW];    // 2.3 KB merge scratch 2
    __shared__ unsigned bnd[ROWS_PB];
    __shared__ float    red[ROWS_PB];

    const int t = threadIdx.x;
    const int lane = t & (LANES - 1);
    const int w = t >> 6;                       // 0..7 (wave id = octant)

    // Own-row coefficients -> SGPRs (wave-uniform; canonical d2 = s + cW
    // where s = fmaf(cX,qx, fmaf(cY,qy, fmaf(cZ,qz, qw)))).
    float cX[RPT], cY[RPT], cZ[RPT], cW[RPT];
#pragma unroll
    for (int i = 0; i < RPT; ++i) {
        float4 p = sm4[blockIdx.x * ROWS_PB + i];
        cX[i] = sfl(-2.0f * p.x);
        cY[i] = sfl(-2.0f * p.y);
        cZ[i] = sfl(-2.0f * p.z);
        cW[i] = sfl(p.w);
    }

    // ---- Bound: per-lane packed min over 4-cand slices of the octant's
    // first 256 cands (8 octants -> 2048-cand sample). Fold lanes ^32,^16
    // -> 128 minima/row (each the min of 16 distinct candidates).
    // Direct global loads (short phase, VGPR-light, retires in-order
    // before the scan so scan-side vmcnt arithmetic starts at 0).
    {
        unsigned pm[RPT];
#pragma unroll
        for (int i = 0; i < RPT; ++i) pm[i] = 0xFFFFFFFFu;
        const int b0 = w * (KQT * LANES);
        const float4* __restrict__ bp = sm4 + b0 + lane;
#pragma unroll
        for (int k = 0; k < BNDI; ++k) {
            const int ci = b0 + k * LANES + lane;
            float4 q = bp[k * LANES];
#pragma unroll
            for (int i = 0; i < RPT; ++i) {
                float s = fmaf(cX[i], q.x,
                          fmaf(cY[i], q.y, fmaf(cZ[i], q.z, q.w)));
                pm[i] = umn(pm[i], pack_d2(s + cW[i], ci));  // canonical d2
            }
        }
#pragma unroll
        for (int i = 0; i < RPT; ++i) {
            pm[i] = umn(pm[i], (unsigned)__shfl_xor((int)pm[i], 32, 64));
            pm[i] = umn(pm[i], (unsigned)__shfl_xor((int)pm[i], 16, 64));
        }
        if (lane < 16) {
#pragma unroll
            for (int i = 0; i < RPT; ++i)
                bpart[i * BP + w * 16 + lane] = pm[i];
        }
    }
    __syncthreads();

    // Merge 128 minima/row -> bnd = 9th smallest (valid upper bound on the
    // row's true 9th: the 9 minima below it are 9 distinct candidates).
    if (t < 128) {                              // stage 1: 8 rows x 16 groups
        const int r1 = t & (ROWS_PB - 1);
        const int g = t >> 3;                   // 0..15
        unsigned s[KSEL];
#pragma unroll
        for (int k = 0; k < KSEL; ++k) s[k] = 0xFFFFFFFFu;
#pragma unroll
        for (int e = 0; e < 8; ++e)
            insert9(s, bpart[r1 * BP + g * 8 + e]);
#pragma unroll
        for (int k = 0; k < KSEL; ++k)
            scratch[r1 * SROW + g * KSEL + k] = s[k];
    }
    __syncthreads();
    if (t < 64) {                               // stage 2: 8 rows x 8 groups
        const int r1 = t & (ROWS_PB - 1);
        const int mg = t >> 3;                  // 0..7
        unsigned m[KSEL];
#pragma unroll
        for (int k = 0; k < KSEL; ++k) m[k] = 0xFFFFFFFFu;
#pragma unroll
        for (int e = 0; e < 2 * KSEL; ++e)
            insert9(m, scratch[r1 * SROW + (2 * mg) * KSEL + e]);
#pragma unroll
        for (int k = 0; k < KSEL; ++k)
            partS[r1 * PROW + mg * KSEL + k] = m[k];
    }
    __syncthreads();
    if (t < ROWS_PB) {                          // stage 3: 72 -> 9th
        unsigned m[KSEL];
#pragma unroll
        for (int k = 0; k < KSEL; ++k) m[k] = 0xFFFFFFFFu;
#pragma unroll
        for (int e = 0; e < 8 * KSEL; ++e)
            insert9(m, partS[t * PROW + e]);
        bnd[t] = m[0];
    }
    __syncthreads();

    // s-space screen bound: pack(d2)|idx <= b requires d2 <= bf where
    // bf = uint_as_float(b | IDX_MASK) (positive floats: uint order == float
    // order). d2 = fl(s + cW) <= bf  ==>  s <= (bf - cW) + ~ulp slack; the
    // relative loosening (on bf AND the difference) keeps sb a superset
    // bound under all cancellation cases. Extras are harmless.
    float sb[RPT];
#pragma unroll
    for (int i = 0; i < RPT; ++i) {
        float bfv = __uint_as_float(bnd[i] | IDX_MASK);
        float D = bfv - cW[i];
        sb[i] = sfl(D + (bfv + fabsf(D)) * 6.0e-7f + 1e-33f);
    }

    // ---- Scan: LDS-staged octant stream, double-buffered, counted vmcnt --
    unsigned base[RPT];
#pragma unroll
    for (int i = 0; i < RPT; ++i) base[i] = 0u;

    const int s0 = w * (KQT * LANES);
    const float4* __restrict__ gsrc = sm4 + s0;

    // Prologue: chunk 0 -> buf 0.
    load_lds16(gsrc + lane,      &stg[w][0][0]);
    load_lds16(gsrc + 64 + lane, &stg[w][0][64]);

#pragma unroll 1
    for (int c = 0; c < NCHUNK; ++c) {
        // Issue chunk c+1 into the other buffer. c=7 over-issues one chunk
        // (w=7 source lands in ss4 -- allocated, value never consumed) so
        // the body stays branch-free and vmcnt(2) is correct on every iter.
        const float4* gn = gsrc + (c + 1) * CHUNK;
        float4* ln = &stg[w][(c + 1) & 1][0];
        load_lds16(gn + lane,      ln);
        load_lds16(gn + 64 + lane, ln + 64);

        // Chunk c's 2 loads retired (in-order) once <=2 remain outstanding.
        asm volatile("s_waitcnt vmcnt(2)" ::: "memory");
        __builtin_amdgcn_sched_barrier(0);

        const float4* buf = &stg[w][c & 1][0];
        float4 q0 = buf[lane];
        float4 q1 = buf[64 + lane];
        const int ci0 = s0 + c * CHUNK + lane;
        QUAD(0, q0, ci0)
        QUAD(4, q0, ci0)
        QUAD(0, q1, ci0 + 64)
        QUAD(4, q1, ci0 + 64)
    }

    if (lane == 0) {
#pragma unroll
        for (int i = 0; i < RPT; ++i)
            wcnt[w * RPT + i] = umn(base[i], WCAP);
    }
    __syncthreads();                             // survivor lists complete
                                                 // (compiler drains vmcnt here)

    // ---- Select: 64 tasks, each merges one (wave,row) list ---------------
    if (t < 64) {
        const int r1 = t & (ROWS_PB - 1);        // row
        const int wv = t >> 3;                   // 0..7 octant wave
        const int li = wv * RPT + r1;
        const unsigned n = wcnt[li];
        unsigned s[KSEL];
#pragma unroll
        for (int k = 0; k < KSEL; ++k) s[k] = 0xFFFFFFFFu;
        for (unsigned k = 0; k < n; ++k)
            insert9(s, wl[li * WCAP + k]);
#pragma unroll
        for (int k = 0; k < KSEL; ++k)
            partS[r1 * PROW + wv * KSEL + k] = s[k];
    }
    __syncthreads();

    if (t < ROWS_PB) {                          // final 72-merge + epilogue
        unsigned m[KSEL];
#pragma unroll
        for (int k = 0; k < KSEL; ++k) m[k] = 0xFFFFFFFFu;
#pragma unroll
        for (int e = 0; e < 8 * KSEL; ++e)
            insert9(m, partS[t * PROW + e]);

        // m[8] = global min (self, or identical-coordinate dup whose term is
        // 0 either way) -> dropped. m[0..7] = the 8 neighbors.
        const int gr = blockIdx.x * ROWS_PB + t;
        float4 pm4 = sm4[gr];
        float4 ps4 = ss4[gr];
        float acc = 0.0f;
#pragma unroll
        for (int k = 0; k < KNN; ++k) {
            int j = (int)(m[k] & IDX_MASK);
            float4 qm = sm4[j];
            float dx = pm4.x - qm.x, dy = pm4.y - qm.y, dz = pm4.z - qm.z;
            float d2 = fmaf(dx, dx, fmaf(dy, dy, dz * dz));
            float d = sqrtf(fmaxf(d2, EPS_F));
            float wgt = expf(-d);
            float4 qs = ss4[j];
            float ax = ps4.x - qs.x, ay = ps4.y - qs.y, az = ps4.z - qs.z;
            acc += wgt * (ax * ax + ay * ay + az * az);
        }
        red[t] = acc;
    }
    __syncthreads();
    if (t == 0) {
        float ssum = 0.0f;
#pragma unroll
        for (int i = 0; i < ROWS_PB; ++i) ssum += red[i];
        partial[blockIdx.x] = ssum;              // plain store
    }
}

// ---------------------------------------------------------------------------
// Kernel 3: reduce 1024 block partials -> scalar (cost ~0, proven R15;
// kept deterministic/order-identical so the output stays bit-exact).
// ---------------------------------------------------------------------------
__global__ __launch_bounds__(256) void reduce_k(
    const float* __restrict__ partial, float* __restrict__ out)
{
    __shared__ float sbuf[4];
    int t = threadIdx.x;
    float v = 0.0f;
    for (int i = t; i < NBLOCKS; i += 256) v += partial[i];
    for (int off = 32; off > 0; off >>= 1) v += __shfl_down(v, off);
    if ((t & 63) == 0) sbuf[t >> 6] = v;
    __syncthreads();
    if (t == 0) {
        float s = sbuf[0] + sbuf[1] + sbuf[2] + sbuf[3];
        out[0] = s * SCALE;
    }
}

// ---------------------------------------------------------------------------
extern "C" void kernel_launch(void* const* d_in, const int* in_sizes, int n_in,
                              void* d_out, int out_size, void* d_ws, size_t ws_size,
                              hipStream_t stream)
{
    const float* means = (const float*)d_in[0];
    const float* sh0   = (const float*)d_in[1];
    const int*   idxp  = (const int*)d_in[2];

    float4* sm4 = (float4*)d_ws;                 // 128 KB
    float4* ss4 = sm4 + NSAMPLE;                 // 128 KB
    float*  partial = (float*)(ss4 + NSAMPLE);   // 4 KB

    gather_k<<<NSAMPLE / 256, 256, 0, stream>>>(means, sh0, idxp, sm4, ss4);
    main_k<<<NBLOCKS, BLK, 0, stream>>>(sm4, ss4, partial);
    reduce_k<<<1, 256, 0, stream>>>(partial, (float*)d_out);
}

// Round 8
// 101.636 us; speedup vs baseline: 1.1275x; 1.0500x over previous
//
#include <hip/hip_runtime.h>
#include <float.h>
#include <math.h>

#define NSAMPLE 8192
#define KSEL 9          // K+1: keep 9 smallest incl. self
#define KNN 8
#define BLK 512
#define EPS_F 1e-12f

#define ROWS_PB 8                    // rows per block -> 1024 blocks
#define NBLOCKS (NSAMPLE / ROWS_PB)  // 1024
#define RPT 8                        // all 8 rows per thread (octant scan)
#define LANES 64
#define KQT 16                       // scan iters per wave (1024-cand octant / 64)
#define CHUNK 64                     // staged cands per chunk (1 per lane)
#define NCHUNK (1024 / CHUNK)        // 16
#define BNDI 4                       // bound iters per wave (256 of the octant)
#define WCAP 32                      // survivor cap per (wave,row) list
#define BP 129                       // bound minima stride (128 + 1 pad)
#define IDX_MASK 0x1FFFu             // low 13 bits = candidate index
#define VAL_MASK 0xFFFFE000u         // high 19 bits = d2 (sign+exp+10 mantissa)
#define PROW 73                      // merge-row stride (72 + 1 pad)
#define SROW 145                     // scratch stride (16*9 + 1)
#define SCALE (1.0f / (float)(NSAMPLE * KNN * 3))

__device__ __forceinline__ unsigned umn(unsigned a, unsigned b) { return a < b ? a : b; }
__device__ __forceinline__ unsigned umx(unsigned a, unsigned b) { return a > b ? a : b; }

// Branchless insert of x into descending-sorted s[0..8] (s[0]=worst, s[8]=best).
__device__ __forceinline__ void insert9(unsigned s[KSEL], unsigned x)
{
#pragma unroll
    for (int k = 0; k < KSEL - 1; ++k)
        s[k] = umx(s[k + 1], umn(x, s[k]));
    s[KSEL - 1] = umn(x, s[KSEL - 1]);
}

// Packed (d2 | idx). d2 clamped >= 0 so self packs minimal.
__device__ __forceinline__ unsigned pack_d2(float d2, int gidx)
{
    return (__float_as_uint(fmaxf(d2, 0.0f)) & VAL_MASK) | (unsigned)gidx;
}

// Force a wave-uniform float into an SGPR (frees per-lane VGPR copies).
__device__ __forceinline__ float sfl(float x)
{
    return __uint_as_float((unsigned)__builtin_amdgcn_readfirstlane(
        (int)__float_as_uint(x)));
}

// popcount(mask & lanes_below_me) in 2 VALU (v_mbcnt_lo/hi).
__device__ __forceinline__ unsigned mbcnt64(unsigned long long m)
{
    return __builtin_amdgcn_mbcnt_hi((unsigned)(m >> 32),
           __builtin_amdgcn_mbcnt_lo((unsigned)(m & 0xFFFFFFFFull), 0u));
}

// Direct global->LDS DMA (gfx950): per-lane global src, wave-uniform LDS
// base; HW writes lane i's 16B at base + i*16. No VGPR destination =>
// regalloc cannot spill or sink it (the R20-R22 failure modes).
__device__ __forceinline__ void load_lds16(const float4* g, float4* l)
{
    __builtin_amdgcn_global_load_lds(
        (const __attribute__((address_space(1))) void*)g,
        (__attribute__((address_space(3))) void*)l, 16, 0, 0);
}

// ---------------------------------------------------------------------------
// Kernel 1: one-time gather into compact L2-resident float4 arrays:
//   sm4 = (mean.xyz, |mean|^2), ss4 = (sh0.xyz, 0).
// ---------------------------------------------------------------------------
__global__ __launch_bounds__(256) void gather_k(
    const float* __restrict__ means, const float* __restrict__ sh0,
    const int* __restrict__ idx,
    float4* __restrict__ sm4, float4* __restrict__ ss4)
{
    int i = blockIdx.x * 256 + threadIdx.x;
    if (i >= NSAMPLE) return;
    int id = idx[i];
    const float* m = means + 3 * id;
    const float* s = sh0 + 3 * id;
    float mx = m[0], my = m[1], mz = m[2];
    sm4[i] = make_float4(mx, my, mz, fmaf(mx, mx, fmaf(my, my, mz * mz)));
    ss4[i] = make_float4(s[0], s[1], s[2], 0.0f);
}

// ---------------------------------------------------------------------------
// Kernel 2 (R24): R23's LDS-staged scan (first clean run of the deep-
// prefetch mechanism: no spill, main_k 46.7->41.7, VALUBusy 38->48) with
// the GEOMETRY fixed. R23 post-mortem: LDS 52.7KB -> 3 blocks/CU resident
// vs a 4 blocks/CU grid -> 256-block tail round (~1.33x makespan stretch),
// OccupancyPercent 40%. R24: CHUNK 128->64 (1 float4/lane) halves staging
// LDS to 16KB; total ~35.3KB -> 4 blocks/CU = zero tail, 32 waves/CU.
// vmcnt discipline unchanged (issue chunk c+1 = 1 load; vmcnt(1) retires
// chunk c; c+1 stays in flight across the body). Per-wave issue->consume
// cover shrinks to ~130cy; the restored 8 waves/SIMD TLP covers the rest --
// structurally every wave ALWAYS has one load in flight, unlike R19 where
// the compiler's depth-2 window serialized load->use per candidate.
// Tripwires: FETCH ~1.2MB / WRITE 32KB / VGPR <=48.
// Screen/packing/dup semantics bit-inherited from R19 -> selection exact.
// ---------------------------------------------------------------------------
// Process rows R..R+3 (R = literal 0 or 4) of one candidate register Q.
#define QUAD(R, Q, CI)                                                        \
    {                                                                         \
        float v0 = fmaf(cX[(R) + 0], (Q).x, fmaf(cY[(R) + 0], (Q).y,          \
                   fmaf(cZ[(R) + 0], (Q).z, (Q).w)));                         \
        float v1 = fmaf(cX[(R) + 1], (Q).x, fmaf(cY[(R) + 1], (Q).y,          \
                   fmaf(cZ[(R) + 1], (Q).z, (Q).w)));                         \
        float v2 = fmaf(cX[(R) + 2], (Q).x, fmaf(cY[(R) + 2], (Q).y,          \
                   fmaf(cZ[(R) + 2], (Q).z, (Q).w)));                         \
        float v3 = fmaf(cX[(R) + 3], (Q).x, fmaf(cY[(R) + 3], (Q).y,          \
                   fmaf(cZ[(R) + 3], (Q).z, (Q).w)));                         \
        unsigned long long m0 = __ballot(v0 <= sb[(R) + 0]);                  \
        unsigned long long m1 = __ballot(v1 <= sb[(R) + 1]);                  \
        unsigned long long m2 = __ballot(v2 <= sb[(R) + 2]);                  \
        unsigned long long m3 = __ballot(v3 <= sb[(R) + 3]);                  \
        if (m0) {                                                             \
            unsigned pos = base[(R) + 0] + mbcnt64(m0);                       \
            if ((v0 <= sb[(R) + 0]) && pos < WCAP)                            \
                wl[(w * RPT + (R) + 0) * WCAP + pos] =                        \
                    pack_d2(v0 + cW[(R) + 0], (CI));                          \
            base[(R) + 0] += (unsigned)__popcll(m0);                          \
        }                                                                     \
        if (m1) {                                                             \
            unsigned pos = base[(R) + 1] + mbcnt64(m1);                       \
            if ((v1 <= sb[(R) + 1]) && pos < WCAP)                            \
                wl[(w * RPT + (R) + 1) * WCAP + pos] =                        \
                    pack_d2(v1 + cW[(R) + 1], (CI));                          \
            base[(R) + 1] += (unsigned)__popcll(m1);                          \
        }                                                                     \
        if (m2) {                                                             \
            unsigned pos = base[(R) + 2] + mbcnt64(m2);                       \
            if ((v2 <= sb[(R) + 2]) && pos < WCAP)                            \
                wl[(w * RPT + (R) + 2) * WCAP + pos] =                        \
                    pack_d2(v2 + cW[(R) + 2], (CI));                          \
            base[(R) + 2] += (unsigned)__popcll(m2);                          \
        }                                                                     \
        if (m3) {                                                             \
            unsigned pos = base[(R) + 3] + mbcnt64(m3);                       \
            if ((v3 <= sb[(R) + 3]) && pos < WCAP)                            \
                wl[(w * RPT + (R) + 3) * WCAP + pos] =                        \
                    pack_d2(v3 + cW[(R) + 3], (CI));                          \
            base[(R) + 3] += (unsigned)__popcll(m3);                          \
        }                                                                     \
    }

__global__ __launch_bounds__(BLK, 8) void main_k(
    const float4* __restrict__ sm4, const float4* __restrict__ ss4,
    float* __restrict__ partial)
{
    __shared__ float4   stg[8][2][CHUNK];         // 16 KB staging (per-wave dbuf)
    __shared__ unsigned wl[8 * RPT * WCAP];       // 8 KB private survivor lists
    __shared__ unsigned wcnt[8 * RPT];
    __shared__ unsigned bpart[ROWS_PB * BP];      // 4.1 KB bound minima (folded)
    __shared__ unsigned scratch[ROWS_PB * SROW];  // 4.6 KB bound-merge scratch
    __shared__ unsigned partS[ROWS_PB * PROW];    // 2.3 KB merge scratch 2
    __shared__ unsigned bnd[ROWS_PB];
    __shared__ float    red[ROWS_PB];

    const int t = threadIdx.x;
    const int lane = t & (LANES - 1);
    const int w = t >> 6;                       // 0..7 (wave id = octant)

    // Own-row coefficients -> SGPRs (wave-uniform; canonical d2 = s + cW
    // where s = fmaf(cX,qx, fmaf(cY,qy, fmaf(cZ,qz, qw)))).
    float cX[RPT], cY[RPT], cZ[RPT], cW[RPT];
#pragma unroll
    for (int i = 0; i < RPT; ++i) {
        float4 p = sm4[blockIdx.x * ROWS_PB + i];
        cX[i] = sfl(-2.0f * p.x);
        cY[i] = sfl(-2.0f * p.y);
        cZ[i] = sfl(-2.0f * p.z);
        cW[i] = sfl(p.w);
    }

    // ---- Bound: per-lane packed min over 4-cand slices of the octant's
    // first 256 cands (8 octants -> 2048-cand sample). Fold lanes ^32,^16
    // -> 128 minima/row (each the min of 16 distinct candidates).
    // Direct global loads (short phase, retires in-order before the scan
    // so scan-side vmcnt arithmetic starts at 0).
    {
        unsigned pm[RPT];
#pragma unroll
        for (int i = 0; i < RPT; ++i) pm[i] = 0xFFFFFFFFu;
        const int b0 = w * (KQT * LANES);
        const float4* __restrict__ bp = sm4 + b0 + lane;
#pragma unroll
        for (int k = 0; k < BNDI; ++k) {
            const int ci = b0 + k * LANES + lane;
            float4 q = bp[k * LANES];
#pragma unroll
            for (int i = 0; i < RPT; ++i) {
                float s = fmaf(cX[i], q.x,
                          fmaf(cY[i], q.y, fmaf(cZ[i], q.z, q.w)));
                pm[i] = umn(pm[i], pack_d2(s + cW[i], ci));  // canonical d2
            }
        }
#pragma unroll
        for (int i = 0; i < RPT; ++i) {
            pm[i] = umn(pm[i], (unsigned)__shfl_xor((int)pm[i], 32, 64));
            pm[i] = umn(pm[i], (unsigned)__shfl_xor((int)pm[i], 16, 64));
        }
        if (lane < 16) {
#pragma unroll
            for (int i = 0; i < RPT; ++i)
                bpart[i * BP + w * 16 + lane] = pm[i];
        }
    }
    __syncthreads();

    // Merge 128 minima/row -> bnd = 9th smallest (valid upper bound on the
    // row's true 9th: the 9 minima below it are 9 distinct candidates).
    if (t < 128) {                              // stage 1: 8 rows x 16 groups
        const int r1 = t & (ROWS_PB - 1);
        const int g = t >> 3;                   // 0..15
        unsigned s[KSEL];
#pragma unroll
        for (int k = 0; k < KSEL; ++k) s[k] = 0xFFFFFFFFu;
#pragma unroll
        for (int e = 0; e < 8; ++e)
            insert9(s, bpart[r1 * BP + g * 8 + e]);
#pragma unroll
        for (int k = 0; k < KSEL; ++k)
            scratch[r1 * SROW + g * KSEL + k] = s[k];
    }
    __syncthreads();
    if (t < 64) {                               // stage 2: 8 rows x 8 groups
        const int r1 = t & (ROWS_PB - 1);
        const int mg = t >> 3;                  // 0..7
        unsigned m[KSEL];
#pragma unroll
        for (int k = 0; k < KSEL; ++k) m[k] = 0xFFFFFFFFu;
#pragma unroll
        for (int e = 0; e < 2 * KSEL; ++e)
            insert9(m, scratch[r1 * SROW + (2 * mg) * KSEL + e]);
#pragma unroll
        for (int k = 0; k < KSEL; ++k)
            partS[r1 * PROW + mg * KSEL + k] = m[k];
    }
    __syncthreads();
    if (t < ROWS_PB) {                          // stage 3: 72 -> 9th
        unsigned m[KSEL];
#pragma unroll
        for (int k = 0; k < KSEL; ++k) m[k] = 0xFFFFFFFFu;
#pragma unroll
        for (int e = 0; e < 8 * KSEL; ++e)
            insert9(m, partS[t * PROW + e]);
        bnd[t] = m[0];
    }
    __syncthreads();

    // s-space screen bound: pack(d2)|idx <= b requires d2 <= bf where
    // bf = uint_as_float(b | IDX_MASK) (positive floats: uint order == float
    // order). d2 = fl(s + cW) <= bf  ==>  s <= (bf - cW) + ~ulp slack; the
    // relative loosening (on bf AND the difference) keeps sb a superset
    // bound under all cancellation cases. Extras are harmless.
    float sb[RPT];
#pragma unroll
    for (int i = 0; i < RPT; ++i) {
        float bfv = __uint_as_float(bnd[i] | IDX_MASK);
        float D = bfv - cW[i];
        sb[i] = sfl(D + (bfv + fabsf(D)) * 6.0e-7f + 1e-33f);
    }

    // ---- Scan: LDS-staged octant stream, double-buffered, counted vmcnt --
    unsigned base[RPT];
#pragma unroll
    for (int i = 0; i < RPT; ++i) base[i] = 0u;

    const int s0 = w * (KQT * LANES);
    const float4* __restrict__ gsrc = sm4 + s0;

    // Prologue: chunk 0 -> buf 0.
    load_lds16(gsrc + lane, &stg[w][0][0]);

#pragma unroll 1
    for (int c = 0; c < NCHUNK; ++c) {
        // Issue chunk c+1 into the other buffer. c=15 over-issues one chunk
        // (w=7 source lands in ss4 -- allocated, value never consumed) so
        // the body stays branch-free and vmcnt(1) is correct on every iter.
        load_lds16(gsrc + (c + 1) * CHUNK + lane, &stg[w][(c + 1) & 1][0]);

        // Chunk c's load retired (in-order) once <=1 remains outstanding.
        asm volatile("s_waitcnt vmcnt(1)" ::: "memory");
        __builtin_amdgcn_sched_barrier(0);

        float4 q0 = stg[w][c & 1][lane];
        const int ci0 = s0 + c * CHUNK + lane;
        QUAD(0, q0, ci0)
        QUAD(4, q0, ci0)
    }

    if (lane == 0) {
#pragma unroll
        for (int i = 0; i < RPT; ++i)
            wcnt[w * RPT + i] = umn(base[i], WCAP);
    }
    __syncthreads();                             // survivor lists complete
                                                 // (compiler drains vmcnt here)

    // ---- Select: 64 tasks, each merges one (wave,row) list ---------------
    if (t < 64) {
        const int r1 = t & (ROWS_PB - 1);        // row
        const int wv = t >> 3;                   // 0..7 octant wave
        const int li = wv * RPT + r1;
        const unsigned n = wcnt[li];
        unsigned s[KSEL];
#pragma unroll
        for (int k = 0; k < KSEL; ++k) s[k] = 0xFFFFFFFFu;
        for (unsigned k = 0; k < n; ++k)
            insert9(s, wl[li * WCAP + k]);
#pragma unroll
        for (int k = 0; k < KSEL; ++k)
            partS[r1 * PROW + wv * KSEL + k] = s[k];
    }
    __syncthreads();

    if (t < ROWS_PB) {                          // final 72-merge + epilogue
        unsigned m[KSEL];
#pragma unroll
        for (int k = 0; k < KSEL; ++k) m[k] = 0xFFFFFFFFu;
#pragma unroll
        for (int e = 0; e < 8 * KSEL; ++e)
            insert9(m, partS[t * PROW + e]);

        // m[8] = global min (self, or identical-coordinate dup whose term is
        // 0 either way) -> dropped. m[0..7] = the 8 neighbors.
        const int gr = blockIdx.x * ROWS_PB + t;
        float4 pm4 = sm4[gr];
        float4 ps4 = ss4[gr];
        float acc = 0.0f;
#pragma unroll
        for (int k = 0; k < KNN; ++k) {
            int j = (int)(m[k] & IDX_MASK);
            float4 qm = sm4[j];
            float dx = pm4.x - qm.x, dy = pm4.y - qm.y, dz = pm4.z - qm.z;
            float d2 = fmaf(dx, dx, fmaf(dy, dy, dz * dz));
            float d = sqrtf(fmaxf(d2, EPS_F));
            float wgt = expf(-d);
            float4 qs = ss4[j];
            float ax = ps4.x - qs.x, ay = ps4.y - qs.y, az = ps4.z - qs.z;
            acc += wgt * (ax * ax + ay * ay + az * az);
        }
        red[t] = acc;
    }
    __syncthreads();
    if (t == 0) {
        float ssum = 0.0f;
#pragma unroll
        for (int i = 0; i < ROWS_PB; ++i) ssum += red[i];
        partial[blockIdx.x] = ssum;              // plain store
    }
}

// ---------------------------------------------------------------------------
// Kernel 3: reduce 1024 block partials -> scalar (cost ~0, proven R15;
// kept deterministic/order-identical so the output stays bit-exact).
// ---------------------------------------------------------------------------
__global__ __launch_bounds__(256) void reduce_k(
    const float* __restrict__ partial, float* __restrict__ out)
{
    __shared__ float sbuf[4];
    int t = threadIdx.x;
    float v = 0.0f;
    for (int i = t; i < NBLOCKS; i += 256) v += partial[i];
    for (int off = 32; off > 0; off >>= 1) v += __shfl_down(v, off);
    if ((t & 63) == 0) sbuf[t >> 6] = v;
    __syncthreads();
    if (t == 0) {
        float s = sbuf[0] + sbuf[1] + sbuf[2] + sbuf[3];
        out[0] = s * SCALE;
    }
}

// ---------------------------------------------------------------------------
extern "C" void kernel_launch(void* const* d_in, const int* in_sizes, int n_in,
                              void* d_out, int out_size, void* d_ws, size_t ws_size,
                              hipStream_t stream)
{
    const float* means = (const float*)d_in[0];
    const float* sh0   = (const float*)d_in[1];
    const int*   idxp  = (const int*)d_in[2];

    float4* sm4 = (float4*)d_ws;                 // 128 KB
    float4* ss4 = sm4 + NSAMPLE;                 // 128 KB
    float*  partial = (float*)(ss4 + NSAMPLE);   // 4 KB

    gather_k<<<NSAMPLE / 256, 256, 0, stream>>>(means, sh0, idxp, sm4, ss4);
    main_k<<<NBLOCKS, BLK, 0, stream>>>(sm4, ss4, partial);
    reduce_k<<<1, 256, 0, stream>>>(partial, (float*)d_out);
}

// Round 9
// 99.243 us; speedup vs baseline: 1.1547x; 1.0241x over previous
//
#include <hip/hip_runtime.h>
#include <float.h>
#include <math.h>

#define NSAMPLE 8192
#define KSEL 9          // K+1: keep 9 smallest incl. self
#define KNN 8
#define BLK 512
#define EPS_F 1e-12f

#define ROWS_PB 8                    // rows per block -> 1024 blocks
#define NBLOCKS (NSAMPLE / ROWS_PB)  // 1024
#define RPT 8                        // all 8 rows per thread (octant scan)
#define LANES 64
#define KQT 16                       // scan iters per wave (1024-cand octant / 64)
#define CHUNK 128                    // staged cands per chunk (2 per lane, R23 rate)
#define NCHUNK (1024 / CHUNK)        // 8
#define BNDI 4                       // bound iters per wave (256 of the octant)
#define WCAP 28                      // survivor cap per (wave,row) list (lambda~4.5)
#define BP 129                       // bound minima stride (128 + 1 pad)
#define IDX_MASK 0x1FFFu             // low 13 bits = candidate index
#define VAL_MASK 0xFFFFE000u         // high 19 bits = d2 (sign+exp+10 mantissa)
#define PROW 73                      // merge-row stride (72 + 1 pad)
#define SROW 145                     // scratch stride (16*9 + 1)
#define SCALE (1.0f / (float)(NSAMPLE * KNN * 3))

// ---- LDS union layout (bytes). Ladder scratch is TEMPORALLY DEAD before
// the first staging write (ladder -> barrier -> sb -> prologue load), so
// staging overlays it. partS is reused by the select phase, when staging
// is dead again. Total 40256 B -> 40448 alloc -> exactly 4 blocks/CU.
//   [0,     32768)  staging float4 [8 waves][2 bufs][128]   (scan)
//   [0,      4128)  bpart   u32 [8*129]                     (ladder)
//   [4128,   8768)  scratch u32 [8*145]                     (ladder)
//   [8768,  11104)  partS   u32 [8*73]                      (ladder + select)
//   [32768, 39936)  wl      u32 [64 lists * 28]             (scan + select)
//   [39936, 40192)  wcnt    u32 [64]
//   [40192, 40224)  bnd     u32 [8]
//   [40224, 40256)  red     f32 [8]
#define SMEM_BYTES 40256
#define OFF_SCRATCH 4128
#define OFF_PARTS   8768
#define OFF_WL      32768
#define OFF_WCNT    39936
#define OFF_BND     40192
#define OFF_RED     40224

__device__ __forceinline__ unsigned umn(unsigned a, unsigned b) { return a < b ? a : b; }
__device__ __forceinline__ unsigned umx(unsigned a, unsigned b) { return a > b ? a : b; }

// Branchless insert of x into descending-sorted s[0..8] (s[0]=worst, s[8]=best).
__device__ __forceinline__ void insert9(unsigned s[KSEL], unsigned x)
{
#pragma unroll
    for (int k = 0; k < KSEL - 1; ++k)
        s[k] = umx(s[k + 1], umn(x, s[k]));
    s[KSEL - 1] = umn(x, s[KSEL - 1]);
}

// Packed (d2 | idx). d2 clamped >= 0 so self packs minimal.
__device__ __forceinline__ unsigned pack_d2(float d2, int gidx)
{
    return (__float_as_uint(fmaxf(d2, 0.0f)) & VAL_MASK) | (unsigned)gidx;
}

// Force a wave-uniform float into an SGPR (frees per-lane VGPR copies).
__device__ __forceinline__ float sfl(float x)
{
    return __uint_as_float((unsigned)__builtin_amdgcn_readfirstlane(
        (int)__float_as_uint(x)));
}

// popcount(mask & lanes_below_me) in 2 VALU (v_mbcnt_lo/hi).
__device__ __forceinline__ unsigned mbcnt64(unsigned long long m)
{
    return __builtin_amdgcn_mbcnt_hi((unsigned)(m >> 32),
           __builtin_amdgcn_mbcnt_lo((unsigned)(m & 0xFFFFFFFFull), 0u));
}

// Direct global->LDS DMA (gfx950): per-lane global src, wave-uniform LDS
// base; HW writes lane i's 16B at base + i*16. No VGPR destination =>
// regalloc cannot spill or sink it (the R20-R22 failure modes).
__device__ __forceinline__ void load_lds16(const float4* g, float4* l)
{
    __builtin_amdgcn_global_load_lds(
        (const __attribute__((address_space(1))) void*)g,
        (__attribute__((address_space(3))) void*)l, 16, 0, 0);
}

// ---------------------------------------------------------------------------
// Kernel 1: one-time gather into compact L2-resident float4 arrays:
//   sm4 = (mean.xyz, |mean|^2), ss4 = (sh0.xyz, 0).
// ---------------------------------------------------------------------------
__global__ __launch_bounds__(256) void gather_k(
    const float* __restrict__ means, const float* __restrict__ sh0,
    const int* __restrict__ idx,
    float4* __restrict__ sm4, float4* __restrict__ ss4)
{
    int i = blockIdx.x * 256 + threadIdx.x;
    if (i >= NSAMPLE) return;
    int id = idx[i];
    const float* m = means + 3 * id;
    const float* s = sh0 + 3 * id;
    float mx = m[0], my = m[1], mz = m[2];
    sm4[i] = make_float4(mx, my, mz, fmaf(mx, mx, fmaf(my, my, mz * mz)));
    ss4[i] = make_float4(s[0], s[1], s[2], 0.0f);
}

// ---------------------------------------------------------------------------
// Kernel 2 (R25): R23's scan loop (CHUNK=128: best measured per-wave rate,
// 41.7us at 3 blocks/CU) + R24's geometry (4 blocks/CU, zero tail) via the
// LDS union above. R23/R24 isolated the trade: CHUNK=128 halves per-cand
// loop/vmcnt overhead but its 52.7KB LDS cost a 25% occupancy tail; CHUNK=64
// fixed geometry but paid the overhead back (est ~36us). The ladder scratch
// (11.1KB) is dead before staging's first byte (barrier-separated phases),
// so the 32KB staging overlays it; WCAP 32->28 (lambda~4.5, P(>28)<1e-15)
// frees the rest. One variable changed vs R23/R24: the layout.
// Tripwires: FETCH ~1.2MB / WRITE 32KB / VGPR ~40 / LDS 40448.
// Screen/packing/dup semantics bit-inherited from R19 -> selection exact.
// ---------------------------------------------------------------------------
// Process rows R..R+3 (R = literal 0 or 4) of one candidate register Q.
#define QUAD(R, Q, CI)                                                        \
    {                                                                         \
        float v0 = fmaf(cX[(R) + 0], (Q).x, fmaf(cY[(R) + 0], (Q).y,          \
                   fmaf(cZ[(R) + 0], (Q).z, (Q).w)));                         \
        float v1 = fmaf(cX[(R) + 1], (Q).x, fmaf(cY[(R) + 1], (Q).y,          \
                   fmaf(cZ[(R) + 1], (Q).z, (Q).w)));                         \
        float v2 = fmaf(cX[(R) + 2], (Q).x, fmaf(cY[(R) + 2], (Q).y,          \
                   fmaf(cZ[(R) + 2], (Q).z, (Q).w)));                         \
        float v3 = fmaf(cX[(R) + 3], (Q).x, fmaf(cY[(R) + 3], (Q).y,          \
                   fmaf(cZ[(R) + 3], (Q).z, (Q).w)));                         \
        unsigned long long m0 = __ballot(v0 <= sb[(R) + 0]);                  \
        unsigned long long m1 = __ballot(v1 <= sb[(R) + 1]);                  \
        unsigned long long m2 = __ballot(v2 <= sb[(R) + 2]);                  \
        unsigned long long m3 = __ballot(v3 <= sb[(R) + 3]);                  \
        if (m0) {                                                             \
            unsigned pos = base[(R) + 0] + mbcnt64(m0);                       \
            if ((v0 <= sb[(R) + 0]) && pos < WCAP)                            \
                wl[(w * RPT + (R) + 0) * WCAP + pos] =                        \
                    pack_d2(v0 + cW[(R) + 0], (CI));                          \
            base[(R) + 0] += (unsigned)__popcll(m0);                          \
        }                                                                     \
        if (m1) {                                                             \
            unsigned pos = base[(R) + 1] + mbcnt64(m1);                       \
            if ((v1 <= sb[(R) + 1]) && pos < WCAP)                            \
                wl[(w * RPT + (R) + 1) * WCAP + pos] =                        \
                    pack_d2(v1 + cW[(R) + 1], (CI));                          \
            base[(R) + 1] += (unsigned)__popcll(m1);                          \
        }                                                                     \
        if (m2) {                                                             \
            unsigned pos = base[(R) + 2] + mbcnt64(m2);                       \
            if ((v2 <= sb[(R) + 2]) && pos < WCAP)                            \
                wl[(w * RPT + (R) + 2) * WCAP + pos] =                        \
                    pack_d2(v2 + cW[(R) + 2], (CI));                          \
            base[(R) + 2] += (unsigned)__popcll(m2);                          \
        }                                                                     \
        if (m3) {                                                             \
            unsigned pos = base[(R) + 3] + mbcnt64(m3);                       \
            if ((v3 <= sb[(R) + 3]) && pos < WCAP)                            \
                wl[(w * RPT + (R) + 3) * WCAP + pos] =                        \
                    pack_d2(v3 + cW[(R) + 3], (CI));                          \
            base[(R) + 3] += (unsigned)__popcll(m3);                          \
        }                                                                     \
    }

__global__ __launch_bounds__(BLK, 8) void main_k(
    const float4* __restrict__ sm4, const float4* __restrict__ ss4,
    float* __restrict__ partial)
{
    __shared__ __align__(16) unsigned char smem[SMEM_BYTES];
    float4*   stg     = (float4*)smem;                      // scan staging
    unsigned* bpart   = (unsigned*)smem;                    // ladder (dead later)
    unsigned* scratch = (unsigned*)(smem + OFF_SCRATCH);    // ladder (dead later)
    unsigned* partS   = (unsigned*)(smem + OFF_PARTS);      // ladder + select
    unsigned* wl      = (unsigned*)(smem + OFF_WL);
    unsigned* wcnt    = (unsigned*)(smem + OFF_WCNT);
    unsigned* bnd     = (unsigned*)(smem + OFF_BND);
    float*    red     = (float*)(smem + OFF_RED);

    const int t = threadIdx.x;
    const int lane = t & (LANES - 1);
    const int w = t >> 6;                       // 0..7 (wave id = octant)

    // Own-row coefficients -> SGPRs (wave-uniform; canonical d2 = s + cW
    // where s = fmaf(cX,qx, fmaf(cY,qy, fmaf(cZ,qz, qw)))).
    float cX[RPT], cY[RPT], cZ[RPT], cW[RPT];
#pragma unroll
    for (int i = 0; i < RPT; ++i) {
        float4 p = sm4[blockIdx.x * ROWS_PB + i];
        cX[i] = sfl(-2.0f * p.x);
        cY[i] = sfl(-2.0f * p.y);
        cZ[i] = sfl(-2.0f * p.z);
        cW[i] = sfl(p.w);
    }

    // ---- Bound: per-lane packed min over 4-cand slices of the octant's
    // first 256 cands (8 octants -> 2048-cand sample). Fold lanes ^32,^16
    // -> 128 minima/row (each the min of 16 distinct candidates).
    {
        unsigned pm[RPT];
#pragma unroll
        for (int i = 0; i < RPT; ++i) pm[i] = 0xFFFFFFFFu;
        const int b0 = w * (KQT * LANES);
        const float4* __restrict__ bp = sm4 + b0 + lane;
#pragma unroll
        for (int k = 0; k < BNDI; ++k) {
            const int ci = b0 + k * LANES + lane;
            float4 q = bp[k * LANES];
#pragma unroll
            for (int i = 0; i < RPT; ++i) {
                float s = fmaf(cX[i], q.x,
                          fmaf(cY[i], q.y, fmaf(cZ[i], q.z, q.w)));
                pm[i] = umn(pm[i], pack_d2(s + cW[i], ci));  // canonical d2
            }
        }
#pragma unroll
        for (int i = 0; i < RPT; ++i) {
            pm[i] = umn(pm[i], (unsigned)__shfl_xor((int)pm[i], 32, 64));
            pm[i] = umn(pm[i], (unsigned)__shfl_xor((int)pm[i], 16, 64));
        }
        if (lane < 16) {
#pragma unroll
            for (int i = 0; i < RPT; ++i)
                bpart[i * BP + w * 16 + lane] = pm[i];
        }
    }
    __syncthreads();

    // Merge 128 minima/row -> bnd = 9th smallest (valid upper bound on the
    // row's true 9th: the 9 minima below it are 9 distinct candidates).
    if (t < 128) {                              // stage 1: 8 rows x 16 groups
        const int r1 = t & (ROWS_PB - 1);
        const int g = t >> 3;                   // 0..15
        unsigned s[KSEL];
#pragma unroll
        for (int k = 0; k < KSEL; ++k) s[k] = 0xFFFFFFFFu;
#pragma unroll
        for (int e = 0; e < 8; ++e)
            insert9(s, bpart[r1 * BP + g * 8 + e]);
#pragma unroll
        for (int k = 0; k < KSEL; ++k)
            scratch[r1 * SROW + g * KSEL + k] = s[k];
    }
    __syncthreads();
    if (t < 64) {                               // stage 2: 8 rows x 8 groups
        const int r1 = t & (ROWS_PB - 1);
        const int mg = t >> 3;                  // 0..7
        unsigned m[KSEL];
#pragma unroll
        for (int k = 0; k < KSEL; ++k) m[k] = 0xFFFFFFFFu;
#pragma unroll
        for (int e = 0; e < 2 * KSEL; ++e)
            insert9(m, scratch[r1 * SROW + (2 * mg) * KSEL + e]);
#pragma unroll
        for (int k = 0; k < KSEL; ++k)
            partS[r1 * PROW + mg * KSEL + k] = m[k];
    }
    __syncthreads();
    if (t < ROWS_PB) {                          // stage 3: 72 -> 9th
        unsigned m[KSEL];
#pragma unroll
        for (int k = 0; k < KSEL; ++k) m[k] = 0xFFFFFFFFu;
#pragma unroll
        for (int e = 0; e < 8 * KSEL; ++e)
            insert9(m, partS[t * PROW + e]);
        bnd[t] = m[0];
    }
    __syncthreads();                            // ladder regions now dead

    // s-space screen bound: pack(d2)|idx <= b requires d2 <= bf where
    // bf = uint_as_float(b | IDX_MASK) (positive floats: uint order == float
    // order). d2 = fl(s + cW) <= bf  ==>  s <= (bf - cW) + ~ulp slack; the
    // relative loosening (on bf AND the difference) keeps sb a superset
    // bound under all cancellation cases. Extras are harmless.
    float sb[RPT];
#pragma unroll
    for (int i = 0; i < RPT; ++i) {
        float bfv = __uint_as_float(bnd[i] | IDX_MASK);
        float D = bfv - cW[i];
        sb[i] = sfl(D + (bfv + fabsf(D)) * 6.0e-7f + 1e-33f);
    }

    // ---- Scan: LDS-staged octant stream (R23 loop verbatim) --------------
    // Issue chunk c+1 (2 loads) -> vmcnt(2) retires chunk c (its 2 loads
    // stay in flight across the body) -> consume 2 staged cands x 8 rows.
    unsigned base[RPT];
#pragma unroll
    for (int i = 0; i < RPT; ++i) base[i] = 0u;

    const int s0 = w * (KQT * LANES);
    const float4* __restrict__ gsrc = sm4 + s0;

    // Prologue: chunk 0 -> buf 0. (Staging writes begin only after the
    // ladder's last barrier -- the union overlay is temporally safe.)
    load_lds16(gsrc + lane,      stg + (w * 2 + 0) * CHUNK);
    load_lds16(gsrc + 64 + lane, stg + (w * 2 + 0) * CHUNK + 64);

#pragma unroll 1
    for (int c = 0; c < NCHUNK; ++c) {
        // Issue chunk c+1 into the other buffer. c=7 over-issues one chunk
        // (w=7 source lands in ss4 -- allocated, value never consumed) so
        // the body stays branch-free and vmcnt(2) is correct on every iter.
        const float4* gn = gsrc + (c + 1) * CHUNK;
        float4* ln = stg + (w * 2 + ((c + 1) & 1)) * CHUNK;
        load_lds16(gn + lane,      ln);
        load_lds16(gn + 64 + lane, ln + 64);

        // Chunk c's 2 loads retired (in-order) once <=2 remain outstanding.
        asm volatile("s_waitcnt vmcnt(2)" ::: "memory");
        __builtin_amdgcn_sched_barrier(0);

        const float4* buf = stg + (w * 2 + (c & 1)) * CHUNK;
        float4 q0 = buf[lane];
        float4 q1 = buf[64 + lane];
        const int ci0 = s0 + c * CHUNK + lane;
        QUAD(0, q0, ci0)
        QUAD(4, q0, ci0)
        QUAD(0, q1, ci0 + 64)
        QUAD(4, q1, ci0 + 64)
    }

    if (lane == 0) {
#pragma unroll
        for (int i = 0; i < RPT; ++i)
            wcnt[w * RPT + i] = umn(base[i], WCAP);
    }
    __syncthreads();                             // survivor lists complete
                                                 // (drains vmcnt; staging dead)

    // ---- Select: 64 tasks, each merges one (wave,row) list ---------------
    if (t < 64) {
        const int r1 = t & (ROWS_PB - 1);        // row
        const int wv = t >> 3;                   // 0..7 octant wave
        const int li = wv * RPT + r1;
        const unsigned n = wcnt[li];
        unsigned s[KSEL];
#pragma unroll
        for (int k = 0; k < KSEL; ++k) s[k] = 0xFFFFFFFFu;
        for (unsigned k = 0; k < n; ++k)
            insert9(s, wl[li * WCAP + k]);
#pragma unroll
        for (int k = 0; k < KSEL; ++k)
            partS[r1 * PROW + wv * KSEL + k] = s[k];
    }
    __syncthreads();

    if (t < ROWS_PB) {                          // final 72-merge + epilogue
        unsigned m[KSEL];
#pragma unroll
        for (int k = 0; k < KSEL; ++k) m[k] = 0xFFFFFFFFu;
#pragma unroll
        for (int e = 0; e < 8 * KSEL; ++e)
            insert9(m, partS[t * PROW + e]);

        // m[8] = global min (self, or identical-coordinate dup whose term is
        // 0 either way) -> dropped. m[0..7] = the 8 neighbors.
        const int gr = blockIdx.x * ROWS_PB + t;
        float4 pm4 = sm4[gr];
        float4 ps4 = ss4[gr];
        float acc = 0.0f;
#pragma unroll
        for (int k = 0; k < KNN; ++k) {
            int j = (int)(m[k] & IDX_MASK);
            float4 qm = sm4[j];
            float dx = pm4.x - qm.x, dy = pm4.y - qm.y, dz = pm4.z - qm.z;
            float d2 = fmaf(dx, dx, fmaf(dy, dy, dz * dz));
            float d = sqrtf(fmaxf(d2, EPS_F));
            float wgt = expf(-d);
            float4 qs = ss4[j];
            float ax = ps4.x - qs.x, ay = ps4.y - qs.y, az = ps4.z - qs.z;
            acc += wgt * (ax * ax + ay * ay + az * az);
        }
        red[t] = acc;
    }
    __syncthreads();
    if (t == 0) {
        float ssum = 0.0f;
#pragma unroll
        for (int i = 0; i < ROWS_PB; ++i) ssum += red[i];
        partial[blockIdx.x] = ssum;              // plain store
    }
}

// ---------------------------------------------------------------------------
// Kernel 3: reduce 1024 block partials -> scalar (cost ~0, proven R15;
// kept deterministic/order-identical so the output stays bit-exact).
// ---------------------------------------------------------------------------
__global__ __launch_bounds__(256) void reduce_k(
    const float* __restrict__ partial, float* __restrict__ out)
{
    __shared__ float sbuf[4];
    int t = threadIdx.x;
    float v = 0.0f;
    for (int i = t; i < NBLOCKS; i += 256) v += partial[i];
    for (int off = 32; off > 0; off >>= 1) v += __shfl_down(v, off);
    if ((t & 63) == 0) sbuf[t >> 6] = v;
    __syncthreads();
    if (t == 0) {
        float s = sbuf[0] + sbuf[1] + sbuf[2] + sbuf[3];
        out[0] = s * SCALE;
    }
}

// ---------------------------------------------------------------------------
extern "C" void kernel_launch(void* const* d_in, const int* in_sizes, int n_in,
                              void* d_out, int out_size, void* d_ws, size_t ws_size,
                              hipStream_t stream)
{
    const float* means = (const float*)d_in[0];
    const float* sh0   = (const float*)d_in[1];
    const int*   idxp  = (const int*)d_in[2];

    float4* sm4 = (float4*)d_ws;                 // 128 KB
    float4* ss4 = sm4 + NSAMPLE;                 // 128 KB
    float*  partial = (float*)(ss4 + NSAMPLE);   // 4 KB

    gather_k<<<NSAMPLE / 256, 256, 0, stream>>>(means, sh0, idxp, sm4, ss4);
    main_k<<<NBLOCKS, BLK, 0, stream>>>(sm4, ss4, partial);
    reduce_k<<<1, 256, 0, stream>>>(partial, (float*)d_out);
}